// Round 10
// baseline (184.169 us; speedup 1.0000x reference)
//
#include <hip/hip_runtime.h>
#include <cstdint>
#include <cstddef>

// ============================================================================
// MildAugmentStage: random-resized-crop (cubic, antialias) + color jitter +
// separable gaussian blur, reproducing jax.random (threefry2x32) exactly.
// Round 9: blur x-pass via aligned-float4 sliding window over an apron-padded
// mid buffer (240 b32 -> ~18 b128 per thread, bit-identical order); resize
// y-weights read directly from uniform global (s_load) instead of LDS bcast.
// ============================================================================

#define JAX_PARTITIONABLE 1

#define NB 256
#define NC 3
#define IH 256
#define IW 256
#define OS 224
#define PIX (OS * OS)         // 50176
#define PSTRIDE 32
#define TROWS 16              // output rows per resize/blur tile
#define LROWS 24              // max staged input rows
#define NTILE 14              // 224/16
#define CSTRIDE 28            // dwords per staged column (112 B)
#define YSTR 25               // y-buffer column stride (gcd(25,32)=1)
#define BSTR 240              // blur mid row stride (8 apron + 224 + 8), 16B-aligned

// ---------------- bf16 helpers ----------------
__device__ __forceinline__ float bf2f(unsigned short u) {
  return __uint_as_float(((unsigned)u) << 16);
}
__device__ __forceinline__ unsigned short f2bf(float f) {
  unsigned u = __float_as_uint(f);
  return (unsigned short)((u + 0x7FFFu + ((u >> 16) & 1u)) >> 16);
}

// ---------------- threefry-2x32 ----------------
__device__ __forceinline__ void tf2x32(uint32_t k0, uint32_t k1,
                                       uint32_t x0, uint32_t x1,
                                       uint32_t& o0, uint32_t& o1) {
  uint32_t ks[3] = {k0, k1, k0 ^ k1 ^ 0x1BD11BDAu};
  uint32_t a = x0 + ks[0], b = x1 + ks[1];
  const int R[2][4] = {{13, 15, 26, 6}, {17, 29, 16, 24}};
  #pragma unroll
  for (int i = 0; i < 5; ++i) {
    #pragma unroll
    for (int j = 0; j < 4; ++j) {
      int r = R[i & 1][j];
      a += b;
      b = (b << r) | (b >> (32 - r));
      b ^= a;
    }
    a += ks[(i + 1) % 3];
    b += ks[(i + 2) % 3] + (uint32_t)(i + 1);
  }
  o0 = a; o1 = b;
}

__device__ __forceinline__ float bits_to_u01(uint32_t bits) {
  uint32_t fb = (bits >> 9) | 0x3f800000u;
  return __uint_as_float(fb) - 1.0f;
}

__device__ __forceinline__ float u01_n(uint32_t k0, uint32_t k1, uint32_t i, uint32_t N) {
#if JAX_PARTITIONABLE
  uint32_t a, b; tf2x32(k0, k1, 0u, i, a, b);
  return bits_to_u01(a ^ b);
#else
  uint32_t half = N >> 1;
  uint32_t a, b;
  if (i < half) { tf2x32(k0, k1, i, half + i, a, b); return bits_to_u01(a); }
  tf2x32(k0, k1, i - half, i, a, b); return bits_to_u01(b);
#endif
}

__device__ __forceinline__ float junif(uint32_t k0, uint32_t k1, uint32_t i, uint32_t N,
                                       float mn, float mx) {
  float u = u01_n(k0, k1, i, N);
  float d = __fsub_rn(mx, mn);
  float r = __fadd_rn(__fmul_rn(u, d), mn);
  return fmaxf(mn, r);
}

// ---------------- per-batch augmentation parameters ----------------
__global__ __launch_bounds__(256) void k_params(float* __restrict__ prm) {
  int b = threadIdx.x;
  if (b >= NB) return;
  uint32_t ks[10][2];
#if JAX_PARTITIONABLE
  for (int j = 0; j < 10; ++j) tf2x32(0u, 42u, 0u, (uint32_t)j, ks[j][0], ks[j][1]);
#else
  {
    uint32_t flat[20];
    for (int j = 0; j < 10; ++j) {
      uint32_t a, bb; tf2x32(0u, 42u, (uint32_t)j, (uint32_t)(10 + j), a, bb);
      flat[j] = a; flat[10 + j] = bb;
    }
    for (int j = 0; j < 10; ++j) { ks[j][0] = flat[2 * j]; ks[j][1] = flat[2 * j + 1]; }
  }
#endif
  float* P = prm + b * PSTRIDE;

  float uarea = junif(ks[0][0], ks[0][1], b, NB, 0.8f, 1.0f);
  float area  = __fmul_rn(65536.0f, uarea);
  float lmn = (float)(-0.28768207245178085);
  float lmx = (float)( 0.28768207245178085);
  float ur  = junif(ks[1][0], ks[1][1], b, NB, lmn, lmx);
  float ratio = (float)exp((double)ur);

  float cw = rintf(__fsqrt_rn(__fmul_rn(area, ratio)));
  cw = fminf(fmaxf(cw, 1.0f), 256.0f);
  float ch = rintf(__fsqrt_rn(__fdiv_rn(area, ratio)));
  ch = fminf(fmaxf(ch, 1.0f), 256.0f);

  float ui = u01_n(ks[2][0], ks[2][1], b, NB);
  float uj = u01_n(ks[3][0], ks[3][1], b, NB);
  float i0 = floorf(__fmul_rn(ui, __fadd_rn(__fsub_rn(256.0f, ch), 1.0f)));
  float j0 = floorf(__fmul_rn(uj, __fadd_rn(__fsub_rn(256.0f, cw), 1.0f)));

  float sy = __fdiv_rn(224.0f, ch), sx = __fdiv_rn(224.0f, cw);
  float ty = -__fmul_rn(i0, sy),   tx = -__fmul_rn(j0, sx);
  float inv_sy = __fdiv_rn(1.0f, sy), inv_sx = __fdiv_rn(1.0f, sx);
  P[0] = inv_sy;
  P[1] = __fmul_rn(ty, inv_sy);
  P[2] = fmaxf(inv_sy, 1.0f);
  P[3] = inv_sx;
  P[4] = __fmul_rn(tx, inv_sx);
  P[5] = fmaxf(inv_sx, 1.0f);

  P[6] = junif(ks[4][0], ks[4][1], b, NB, 0.9f, 1.1f);
  P[7] = junif(ks[5][0], ks[5][1], b, NB, 0.9f, 1.1f);
  P[8] = junif(ks[6][0], ks[6][1], b, NB, 0.9f, 1.1f);
  P[9] = junif(ks[7][0], ks[7][1], b, NB, -0.01f, 0.01f);
  P[10] = (u01_n(ks[8][0], ks[8][1], b, NB) < 0.8f) ? 1.0f : 0.0f;

  uint32_t kb0[2], kb1[2];
#if JAX_PARTITIONABLE
  tf2x32(ks[9][0], ks[9][1], 0u, 0u, kb0[0], kb0[1]);
  tf2x32(ks[9][0], ks[9][1], 0u, 1u, kb1[0], kb1[1]);
#else
  {
    uint32_t f0, s0, f1, s1;
    tf2x32(ks[9][0], ks[9][1], 0u, 2u, f0, s0);
    tf2x32(ks[9][0], ks[9][1], 1u, 3u, f1, s1);
    kb0[0] = f0; kb0[1] = f1; kb1[0] = s0; kb1[1] = s1;
  }
#endif
  float sg = junif(kb0[0], kb0[1], b, NB, 0.1f, 2.0f);
  P[11] = (u01_n(kb1[0], kb1[1], b, NB) < 0.5f) ? 1.0f : 0.0f;

  float e[15]; float ssum = 0.0f;
  for (int k = 0; k < 15; ++k) {
    float t = (float)k - 7.0f;
    float z = t / sg;
    e[k] = expf(-0.5f * (z * z));
    ssum += e[k];
  }
  for (int k = 0; k < 15; ++k) P[12 + k] = e[k] / ssum;
}

// ---------------- cubic (Keys, a=-0.5) ----------------
__device__ __forceinline__ float keys_cubic(float x) {
  float o = ((1.5f * x - 2.5f) * x) * x + 1.0f;
  if (x >= 1.0f) o = ((-0.5f * x + 2.5f) * x - 4.0f) * x + 2.0f;
  if (x >= 2.0f) o = 0.0f;
  return o;
}

// ---------------- per-batch resize weight tables ----------------
// wtab[b][dim(0=y,1=x)][o][8]: w0..w5 (zero-padded), i0, ntaps
__global__ __launch_bounds__(224) void k_weights(const float* __restrict__ prm,
                                                 float* __restrict__ wtab) {
  int o = threadIdx.x;
  int dim = blockIdx.x & 1;
  int b = blockIdx.x >> 1;
  const float* P = prm + b * PSTRIDE;
  float inv = dim ? P[3] : P[0];
  float ti  = dim ? P[4] : P[1];
  float ks  = dim ? P[5] : P[2];
  float sf = ((float)o + 0.5f) * inv - ti - 0.5f;
  float r = 2.0f * ks;
  int i0 = max(0, (int)ceilf(sf - r));
  int i1 = min(255, (int)floorf(sf + r));
  int n = i1 - i0 + 1; if (n > 6) n = 6;
  float w[6]; float tot = 0.0f;
  #pragma unroll
  for (int j = 0; j < 6; ++j) {
    float v = 0.0f;
    if (j < n) { float d = fabsf(sf - (float)(i0 + j)) / ks; v = keys_cubic(d); }
    w[j] = v; tot += v;
  }
  float ri = (fabsf(tot) > 1.1920929e-4f) ? (1.0f / tot) : 0.0f;
  float* W = wtab + ((size_t)(b * 2 + dim) * 224 + o) * 8;
  #pragma unroll
  for (int j = 0; j < 6; ++j) W[j] = w[j] * ri;
  W[6] = (float)i0;
  W[7] = (float)n;
}

// ---------------- tiled separable resize (bf16 out) ----------------
__global__ __launch_bounds__(256) void k_resize(const float* __restrict__ x,
                                                unsigned short* __restrict__ xcj,
                                                float* __restrict__ rowsum,
                                                const float* __restrict__ prm,
                                                const float* __restrict__ wtab) {
  int blk = blockIdx.x;
  int tile = blk % NTILE;
  int c = (blk / NTILE) % NC;
  int b = blk / (NTILE * NC);
  int t = threadIdx.x;
  int oyb = tile * TROWS;
  const float* P = prm + b * PSTRIDE;
  const float* wty = wtab + ((size_t)(b * 2) * 224 + oyb) * 8;   // block-uniform

  __shared__ __align__(16) float s_mem[256 * CSTRIDE];   // 28672 B
  __shared__ float wsum[4];

  int base = (int)wty[6];

  // stage column t: FIXED 6 chunks of 4 rows (row-clamped), b128 writes
  {
    const float* src = x + (size_t)(b * NC + c) * IH * IW + t;
    float* colp = s_mem + t * CSTRIDE;
    #pragma unroll
    for (int k = 0; k < 6; ++k) {
      float4 v;
      v.x = src[(size_t)min(base + 4 * k + 0, IH - 1) * IW];
      v.y = src[(size_t)min(base + 4 * k + 1, IH - 1) * IW];
      v.z = src[(size_t)min(base + 4 * k + 2, IH - 1) * IW];
      v.w = src[(size_t)min(base + 4 * k + 3, IH - 1) * IW];
      *(float4*)(colp + 4 * k) = v;
    }
  }
  __syncthreads();

  // x-pass into registers: FIXED 6 taps (zero-padded weights are exact)
  float xr[LROWS];
  #pragma unroll
  for (int r = 0; r < LROWS; ++r) xr[r] = 0.0f;
  if (t < OS) {
    const float4* W4 = (const float4*)(wtab + ((size_t)(b * 2 + 1) * 224 + t) * 8);
    float4 wA = W4[0], wB = W4[1];
    int ix0 = (int)wB.z;
    #pragma unroll
    for (int j = 0; j < 6; ++j) {
      float wj = (j == 0) ? wA.x : (j == 1) ? wA.y : (j == 2) ? wA.z
               : (j == 3) ? wA.w : (j == 4) ? wB.x : wB.y;
      const float* colp = s_mem + (ix0 + j) * CSTRIDE;
      #pragma unroll
      for (int k = 0; k < 6; ++k) {
        float4 f = *(const float4*)(colp + 4 * k);
        xr[4 * k + 0] += wj * f.x;
        xr[4 * k + 1] += wj * f.y;
        xr[4 * k + 2] += wj * f.z;
        xr[4 * k + 3] += wj * f.w;
      }
    }
  }
  __syncthreads();

  // writeback col-major stride 25 (conflict-free; merges to ds_write2_b32)
  {
    float* colq = s_mem + t * YSTR;
    #pragma unroll
    for (int r = 0; r < LROWS; ++r) colq[r] = xr[r];
  }
  __syncthreads();

  // y-pass: weights read DIRECTLY from uniform global (s_load; off LDS pipe),
  // contiguous column reads (ds_read2 pairs), bf16 stores.
  float bfac = P[6];
  float psum = 0.0f;
  bool act = (t < OS);
  unsigned short* dst = xcj + ((size_t)(b * NC + c) * OS + oyb) * OS + t;
  const float* colq = s_mem + t * YSTR;
  #pragma unroll 2
  for (int i = 0; i < TROWS; ++i) {
    float4 a = *(const float4*)(wty + i * 8);       // uniform -> scalar load
    float4 h = *(const float4*)(wty + i * 8 + 4);
    int ry0 = (int)h.z - base;
    const float* p = colq + ry0;
    float acc = a.x * p[0] + a.y * p[1] + a.z * p[2]
              + a.w * p[3] + h.x * p[4] + h.y * p[5];
    if (act) {
      dst[(size_t)i * OS] = f2bf(acc);
      psum += fminf(fmaxf(acc * bfac, 0.0f), 1.0f);
    }
  }
  for (int off = 32; off > 0; off >>= 1) psum += __shfl_down(psum, off, 64);
  int wid = t >> 6, lane = t & 63;
  if (lane == 0) wsum[wid] = psum;
  __syncthreads();
  if (t == 0) rowsum[blk] = wsum[0] + wsum[1] + wsum[2] + wsum[3];
}

__global__ __launch_bounds__(64) void k_means(const float* __restrict__ rowsum,
                                              float* __restrict__ means) {
  int b = blockIdx.x, t = threadIdx.x;
  float acc = 0.0f;
  if (t < NC * NTILE) {
    int c = t / NTILE;
    float w = (c == 0) ? 0.2989f : ((c == 1) ? 0.587f : 0.114f);
    acc = w * rowsum[b * NC * NTILE + t];
  }
  for (int off = 32; off > 0; off >>= 1) acc += __shfl_down(acc, off, 64);
  if (t == 0) means[b] = acc / (float)PIX;
}

// ---------------- color jitter ----------------
__device__ __forceinline__ float clip01(float x) { return fminf(fmaxf(x, 0.0f), 1.0f); }
__device__ __forceinline__ float fmod1(float x)  { return x - floorf(x); }

__device__ __forceinline__ void jitter_px(float& r, float& g, float& bb,
                                          float mg, float bfac, float cfac,
                                          float sfac, float hfac) {
  r = clip01(r * bfac); g = clip01(g * bfac); bb = clip01(bb * bfac);
  r  = clip01(cfac * r  + (1.0f - cfac) * mg);
  g  = clip01(cfac * g  + (1.0f - cfac) * mg);
  bb = clip01(cfac * bb + (1.0f - cfac) * mg);
  float gray = 0.2989f * r + 0.587f * g + 0.114f * bb;
  r  = clip01(sfac * r  + (1.0f - sfac) * gray);
  g  = clip01(sfac * g  + (1.0f - sfac) * gray);
  bb = clip01(sfac * bb + (1.0f - sfac) * gray);
  float maxc = fmaxf(r, fmaxf(g, bb));
  float minc = fminf(r, fminf(g, bb));
  float v = maxc, d = maxc - minc;
  float s = (maxc > 0.0f) ? (d / maxc) : 0.0f;
  float dn = (d > 0.0f) ? d : 1.0f;
  float rc = (maxc - r) / dn, gc = (maxc - g) / dn, bc2 = (maxc - bb) / dn;
  float h = (maxc == r) ? (bc2 - gc)
          : ((maxc == g) ? (2.0f + rc - bc2) : (4.0f + gc - rc));
  h = (d > 0.0f) ? fmod1(h / 6.0f) : 0.0f;
  h = fmod1(h + hfac);
  float fi = floorf(h * 6.0f);
  float f = h * 6.0f - fi;
  int i = ((int)fi) % 6;
  float pp = v * (1.0f - s);
  float q  = v * (1.0f - s * f);
  float tt = v * (1.0f - s * (1.0f - f));
  switch (i) {
    case 0: r = v;  g = tt; bb = pp; break;
    case 1: r = q;  g = v;  bb = pp; break;
    case 2: r = pp; g = v;  bb = tt; break;
    case 3: r = pp; g = q;  bb = v;  break;
    case 4: r = tt; g = pp; bb = v;  break;
    default: r = v; g = pp; bb = q;  break;
  }
}

// 4 px/thread from bf16 xcj. Blur batches: jitter in place (bf16); skip write
// if cj==false (bits already correct). Non-blur: write f32 out.
__global__ __launch_bounds__(256) void k_jitter(unsigned short* __restrict__ xcj,
                                                const float* __restrict__ means,
                                                const float* __restrict__ prm,
                                                float* __restrict__ out) {
  int idx = blockIdx.x * 256 + threadIdx.x;
  const int QPB = PIX / 4;
  if (idx >= NB * QPB) return;
  int b = idx / QPB, p4 = idx - b * QPB;
  const float* P = prm + b * PSTRIDE;
  float bfac = P[6], cfac = P[7], sfac = P[8], hfac = P[9];
  bool cj = P[10] != 0.0f;
  bool bl = P[11] != 0.0f;
  if (bl && !cj) return;                     // xj == xc, bits already in place
  size_t base4 = ((size_t)b * NC * PIX) / 4 + p4;
  ushort4* in4 = (ushort4*)xcj;
  ushort4 ru = in4[base4];
  ushort4 gu = in4[base4 + PIX / 4];
  ushort4 bu = in4[base4 + 2 * (PIX / 4)];
  float4 r4 = make_float4(bf2f(ru.x), bf2f(ru.y), bf2f(ru.z), bf2f(ru.w));
  float4 g4 = make_float4(bf2f(gu.x), bf2f(gu.y), bf2f(gu.z), bf2f(gu.w));
  float4 b4 = make_float4(bf2f(bu.x), bf2f(bu.y), bf2f(bu.z), bf2f(bu.w));
  if (cj) {
    float mg = means[b];
    float* rp = (float*)&r4; float* gp = (float*)&g4; float* bp = (float*)&b4;
    #pragma unroll
    for (int k = 0; k < 4; ++k) jitter_px(rp[k], gp[k], bp[k], mg, bfac, cfac, sfac, hfac);
  }
  if (bl) {
    ushort4 s;
    s.x = f2bf(r4.x); s.y = f2bf(r4.y); s.z = f2bf(r4.z); s.w = f2bf(r4.w);
    in4[base4] = s;
    s.x = f2bf(g4.x); s.y = f2bf(g4.y); s.z = f2bf(g4.z); s.w = f2bf(g4.w);
    in4[base4 + PIX / 4] = s;
    s.x = f2bf(b4.x); s.y = f2bf(b4.y); s.z = f2bf(b4.z); s.w = f2bf(b4.w);
    in4[base4 + 2 * (PIX / 4)] = s;
  } else {
    float4* dst4 = (float4*)out;
    dst4[base4] = r4;
    dst4[base4 + PIX / 4] = g4;
    dst4[base4 + 2 * (PIX / 4)] = b4;
  }
}

// ---------------- separable gaussian blur (reflect), gated per b ----------
// y-pass: contribution trick (bit-identical). mid stored with 8-float
// reflected aprons at stride 240 -> x-pass = 5 aligned ds_read_b128 per
// 4 outputs (contiguous across lanes, conflict-free), k-ascending sums.
__global__ __launch_bounds__(256) void k_blur(const unsigned short* __restrict__ xcj,
                                              float* __restrict__ out,
                                              const float* __restrict__ prm) {
  int blk = blockIdx.x;
  int tile = blk % NTILE;
  int c = (blk / NTILE) % NC;
  int b = blk / (NTILE * NC);
  const float* P = prm + b * PSTRIDE;
  if (P[11] == 0.0f) return;
  int t = threadIdx.x;
  int oyb = tile * TROWS;

  __shared__ unsigned short s_in[TROWS + 14][228];        // 13,680 B (bf16 halo)
  __shared__ __align__(16) float s_mid[TROWS][BSTR];      // 15,360 B (aproned)

  // weights: uniform scalar loads
  float w[15];
  #pragma unroll
  for (int k = 0; k < 15; ++k) w[k] = P[12 + k];

  const unsigned short* plane = xcj + (size_t)(b * NC + c) * PIX;
  float* oplane = out + (size_t)(b * NC + c) * PIX;

  // stage 30 reflected rows as raw bf16 (ushort4 copies)
  {
    const int RQ = OS / 4;                                // 56 quads per row
    for (int f = t; f < (TROWS + 14) * RQ; f += 256) {
      int r = f / RQ, q = f - r * RQ;
      int yy = oyb - 7 + r;
      yy = (yy < 0) ? -yy : ((yy > OS - 1) ? (2 * (OS - 1) - yy) : yy);
      *(ushort4*)&s_in[r][4 * q] = *(const ushort4*)(plane + (size_t)yy * OS + 4 * q);
    }
  }
  __syncthreads();

  // y-pass: contribution trick — 30 reads, 240 static fmacs, exact FP order.
  // Store into aproned mid; threads near edges also fill reflected aprons.
  if (t < OS) {
    float acc[TROWS];
    #pragma unroll
    for (int i = 0; i < TROWS; ++i) acc[i] = 0.0f;
    #pragma unroll
    for (int r = 0; r < TROWS + 14; ++r) {
      float val = bf2f(s_in[r][t]);
      #pragma unroll
      for (int i = 0; i < TROWS; ++i) {
        if (i <= r && r - i <= 14) acc[i] += w[r - i] * val;
      }
    }
    #pragma unroll
    for (int i = 0; i < TROWS; ++i) {
      s_mid[i][8 + t] = acc[i];
      if (t >= 1 && t <= 7)     s_mid[i][8 - t] = acc[i];      // left apron: v=-t
      if (t >= 216 && t <= 222) s_mid[i][454 - t] = acc[i];    // right: v=446-t
    }
  }
  __syncthreads();

  // x-pass: 4 consecutive outputs per work item, 5 aligned b128 window reads.
  // out[4q+m] = sum_k w[k] * pad[4q + m + k + 1], m=0..3 (k ascending).
  #pragma unroll 1
  for (int it = 0; it < 4; ++it) {
    int f = it * 256 + t;
    if (f < TROWS * 56) {
      int r = f / 56, q = f - r * 56;
      const float* row = &s_mid[r][0];
      float v[20];
      *(float4*)&v[0]  = *(const float4*)(row + 4 * q);
      *(float4*)&v[4]  = *(const float4*)(row + 4 * q + 4);
      *(float4*)&v[8]  = *(const float4*)(row + 4 * q + 8);
      *(float4*)&v[12] = *(const float4*)(row + 4 * q + 12);
      *(float4*)&v[16] = *(const float4*)(row + 4 * q + 16);
      float4 o;
      float* op = (float*)&o;
      #pragma unroll
      for (int m = 0; m < 4; ++m) {
        float acc = 0.0f;
        #pragma unroll
        for (int k = 0; k < 15; ++k) acc += w[k] * v[m + k + 1];
        op[m] = acc;
      }
      *(float4*)(oplane + (size_t)(oyb + r) * OS + 4 * q) = o;
    }
  }
}

// ---------------- launch ----------------
extern "C" void kernel_launch(void* const* d_in, const int* in_sizes, int n_in,
                              void* d_out, int out_size, void* d_ws, size_t ws_size,
                              hipStream_t stream) {
  const float* x = (const float*)d_in[0];
  float* out = (float*)d_out;
  char* ws = (char*)d_ws;

  float* prm    = (float*)ws;                            // 32768 B
  float* rowsum = (float*)(ws + 32768);                  // 43008 B
  float* means  = (float*)(ws + 75776);                  // 1024 B
  float* wtab   = (float*)(ws + 76800);                  // 3670016 B
  unsigned short* xcj = (unsigned short*)(ws + 3746816); // 77070336 B (bf16 xc/xj)

  k_params<<<1, 256, 0, stream>>>(prm);
  k_weights<<<NB * 2, 224, 0, stream>>>(prm, wtab);

  int nblk = NB * NC * NTILE;                            // 10752
  k_resize<<<nblk, 256, 0, stream>>>(x, xcj, rowsum, prm, wtab);  // xc -> xcj
  k_means<<<NB, 64, 0, stream>>>(rowsum, means);

  int nquad = NB * (PIX / 4);                            // 3211264
  k_jitter<<<(nquad + 255) / 256, 256, 0, stream>>>(xcj, means, prm, out);

  k_blur<<<nblk, 256, 0, stream>>>(xcj, out, prm);       // blurred b: xcj -> out
}

// Round 11
// 177.446 us; speedup vs baseline: 1.0379x; 1.0379x over previous
//
#include <hip/hip_runtime.h>
#include <cstdint>
#include <cstddef>

// ============================================================================
// MildAugmentStage: random-resized-crop (cubic, antialias) + color jitter +
// separable gaussian blur, reproducing jax.random (threefry2x32) exactly.
// Round 10: resize reverted EXACTLY to round-8 (s_wyl LDS-broadcast y-weights;
// round-9's uniform-global reads repeated the round-4 non-scalarization trap).
// Blur keeps round-9's aligned-float4 sliding-window x-pass (apron-padded mid).
// ============================================================================

#define JAX_PARTITIONABLE 1

#define NB 256
#define NC 3
#define IH 256
#define IW 256
#define OS 224
#define PIX (OS * OS)         // 50176
#define PSTRIDE 32
#define TROWS 16              // output rows per resize/blur tile
#define LROWS 24              // max staged input rows
#define NTILE 14              // 224/16
#define CSTRIDE 28            // dwords per staged column (112 B)
#define YSTR 25               // y-buffer column stride (gcd(25,32)=1)
#define BSTR 240              // blur mid row stride (8 apron + 224 + 8), 16B-aligned

// ---------------- bf16 helpers ----------------
__device__ __forceinline__ float bf2f(unsigned short u) {
  return __uint_as_float(((unsigned)u) << 16);
}
__device__ __forceinline__ unsigned short f2bf(float f) {
  unsigned u = __float_as_uint(f);
  return (unsigned short)((u + 0x7FFFu + ((u >> 16) & 1u)) >> 16);
}

// ---------------- threefry-2x32 ----------------
__device__ __forceinline__ void tf2x32(uint32_t k0, uint32_t k1,
                                       uint32_t x0, uint32_t x1,
                                       uint32_t& o0, uint32_t& o1) {
  uint32_t ks[3] = {k0, k1, k0 ^ k1 ^ 0x1BD11BDAu};
  uint32_t a = x0 + ks[0], b = x1 + ks[1];
  const int R[2][4] = {{13, 15, 26, 6}, {17, 29, 16, 24}};
  #pragma unroll
  for (int i = 0; i < 5; ++i) {
    #pragma unroll
    for (int j = 0; j < 4; ++j) {
      int r = R[i & 1][j];
      a += b;
      b = (b << r) | (b >> (32 - r));
      b ^= a;
    }
    a += ks[(i + 1) % 3];
    b += ks[(i + 2) % 3] + (uint32_t)(i + 1);
  }
  o0 = a; o1 = b;
}

__device__ __forceinline__ float bits_to_u01(uint32_t bits) {
  uint32_t fb = (bits >> 9) | 0x3f800000u;
  return __uint_as_float(fb) - 1.0f;
}

__device__ __forceinline__ float u01_n(uint32_t k0, uint32_t k1, uint32_t i, uint32_t N) {
#if JAX_PARTITIONABLE
  uint32_t a, b; tf2x32(k0, k1, 0u, i, a, b);
  return bits_to_u01(a ^ b);
#else
  uint32_t half = N >> 1;
  uint32_t a, b;
  if (i < half) { tf2x32(k0, k1, i, half + i, a, b); return bits_to_u01(a); }
  tf2x32(k0, k1, i - half, i, a, b); return bits_to_u01(b);
#endif
}

__device__ __forceinline__ float junif(uint32_t k0, uint32_t k1, uint32_t i, uint32_t N,
                                       float mn, float mx) {
  float u = u01_n(k0, k1, i, N);
  float d = __fsub_rn(mx, mn);
  float r = __fadd_rn(__fmul_rn(u, d), mn);
  return fmaxf(mn, r);
}

// ---------------- per-batch augmentation parameters ----------------
__global__ __launch_bounds__(256) void k_params(float* __restrict__ prm) {
  int b = threadIdx.x;
  if (b >= NB) return;
  uint32_t ks[10][2];
#if JAX_PARTITIONABLE
  for (int j = 0; j < 10; ++j) tf2x32(0u, 42u, 0u, (uint32_t)j, ks[j][0], ks[j][1]);
#else
  {
    uint32_t flat[20];
    for (int j = 0; j < 10; ++j) {
      uint32_t a, bb; tf2x32(0u, 42u, (uint32_t)j, (uint32_t)(10 + j), a, bb);
      flat[j] = a; flat[10 + j] = bb;
    }
    for (int j = 0; j < 10; ++j) { ks[j][0] = flat[2 * j]; ks[j][1] = flat[2 * j + 1]; }
  }
#endif
  float* P = prm + b * PSTRIDE;

  float uarea = junif(ks[0][0], ks[0][1], b, NB, 0.8f, 1.0f);
  float area  = __fmul_rn(65536.0f, uarea);
  float lmn = (float)(-0.28768207245178085);
  float lmx = (float)( 0.28768207245178085);
  float ur  = junif(ks[1][0], ks[1][1], b, NB, lmn, lmx);
  float ratio = (float)exp((double)ur);

  float cw = rintf(__fsqrt_rn(__fmul_rn(area, ratio)));
  cw = fminf(fmaxf(cw, 1.0f), 256.0f);
  float ch = rintf(__fsqrt_rn(__fdiv_rn(area, ratio)));
  ch = fminf(fmaxf(ch, 1.0f), 256.0f);

  float ui = u01_n(ks[2][0], ks[2][1], b, NB);
  float uj = u01_n(ks[3][0], ks[3][1], b, NB);
  float i0 = floorf(__fmul_rn(ui, __fadd_rn(__fsub_rn(256.0f, ch), 1.0f)));
  float j0 = floorf(__fmul_rn(uj, __fadd_rn(__fsub_rn(256.0f, cw), 1.0f)));

  float sy = __fdiv_rn(224.0f, ch), sx = __fdiv_rn(224.0f, cw);
  float ty = -__fmul_rn(i0, sy),   tx = -__fmul_rn(j0, sx);
  float inv_sy = __fdiv_rn(1.0f, sy), inv_sx = __fdiv_rn(1.0f, sx);
  P[0] = inv_sy;
  P[1] = __fmul_rn(ty, inv_sy);
  P[2] = fmaxf(inv_sy, 1.0f);
  P[3] = inv_sx;
  P[4] = __fmul_rn(tx, inv_sx);
  P[5] = fmaxf(inv_sx, 1.0f);

  P[6] = junif(ks[4][0], ks[4][1], b, NB, 0.9f, 1.1f);
  P[7] = junif(ks[5][0], ks[5][1], b, NB, 0.9f, 1.1f);
  P[8] = junif(ks[6][0], ks[6][1], b, NB, 0.9f, 1.1f);
  P[9] = junif(ks[7][0], ks[7][1], b, NB, -0.01f, 0.01f);
  P[10] = (u01_n(ks[8][0], ks[8][1], b, NB) < 0.8f) ? 1.0f : 0.0f;

  uint32_t kb0[2], kb1[2];
#if JAX_PARTITIONABLE
  tf2x32(ks[9][0], ks[9][1], 0u, 0u, kb0[0], kb0[1]);
  tf2x32(ks[9][0], ks[9][1], 0u, 1u, kb1[0], kb1[1]);
#else
  {
    uint32_t f0, s0, f1, s1;
    tf2x32(ks[9][0], ks[9][1], 0u, 2u, f0, s0);
    tf2x32(ks[9][0], ks[9][1], 1u, 3u, f1, s1);
    kb0[0] = f0; kb0[1] = f1; kb1[0] = s0; kb1[1] = s1;
  }
#endif
  float sg = junif(kb0[0], kb0[1], b, NB, 0.1f, 2.0f);
  P[11] = (u01_n(kb1[0], kb1[1], b, NB) < 0.5f) ? 1.0f : 0.0f;

  float e[15]; float ssum = 0.0f;
  for (int k = 0; k < 15; ++k) {
    float t = (float)k - 7.0f;
    float z = t / sg;
    e[k] = expf(-0.5f * (z * z));
    ssum += e[k];
  }
  for (int k = 0; k < 15; ++k) P[12 + k] = e[k] / ssum;
}

// ---------------- cubic (Keys, a=-0.5) ----------------
__device__ __forceinline__ float keys_cubic(float x) {
  float o = ((1.5f * x - 2.5f) * x) * x + 1.0f;
  if (x >= 1.0f) o = ((-0.5f * x + 2.5f) * x - 4.0f) * x + 2.0f;
  if (x >= 2.0f) o = 0.0f;
  return o;
}

// ---------------- per-batch resize weight tables ----------------
// wtab[b][dim(0=y,1=x)][o][8]: w0..w5 (zero-padded), i0, ntaps
__global__ __launch_bounds__(224) void k_weights(const float* __restrict__ prm,
                                                 float* __restrict__ wtab) {
  int o = threadIdx.x;
  int dim = blockIdx.x & 1;
  int b = blockIdx.x >> 1;
  const float* P = prm + b * PSTRIDE;
  float inv = dim ? P[3] : P[0];
  float ti  = dim ? P[4] : P[1];
  float ks  = dim ? P[5] : P[2];
  float sf = ((float)o + 0.5f) * inv - ti - 0.5f;
  float r = 2.0f * ks;
  int i0 = max(0, (int)ceilf(sf - r));
  int i1 = min(255, (int)floorf(sf + r));
  int n = i1 - i0 + 1; if (n > 6) n = 6;
  float w[6]; float tot = 0.0f;
  #pragma unroll
  for (int j = 0; j < 6; ++j) {
    float v = 0.0f;
    if (j < n) { float d = fabsf(sf - (float)(i0 + j)) / ks; v = keys_cubic(d); }
    w[j] = v; tot += v;
  }
  float ri = (fabsf(tot) > 1.1920929e-4f) ? (1.0f / tot) : 0.0f;
  float* W = wtab + ((size_t)(b * 2 + dim) * 224 + o) * 8;
  #pragma unroll
  for (int j = 0; j < 6; ++j) W[j] = w[j] * ri;
  W[6] = (float)i0;
  W[7] = (float)n;
}

// ---------------- tiled separable resize (round-8 exact, bf16 out) --------
__global__ __launch_bounds__(256) void k_resize(const float* __restrict__ x,
                                                unsigned short* __restrict__ xcj,
                                                float* __restrict__ rowsum,
                                                const float* __restrict__ prm,
                                                const float* __restrict__ wtab) {
  int blk = blockIdx.x;
  int tile = blk % NTILE;
  int c = (blk / NTILE) % NC;
  int b = blk / (NTILE * NC);
  int t = threadIdx.x;
  int oyb = tile * TROWS;
  const float* P = prm + b * PSTRIDE;
  const float* wty = wtab + ((size_t)(b * 2) * 224 + oyb) * 8;

  __shared__ __align__(16) float s_mem[256 * CSTRIDE];   // 28672 B
  __shared__ __align__(16) float s_wyl[TROWS * 8];       // 512 B y-weight block
  __shared__ float wsum[4];

  if (t < TROWS * 8) s_wyl[t] = wty[t];

  int base = (int)wty[6];

  // stage column t: FIXED 6 chunks of 4 rows (row-clamped), b128 writes
  {
    const float* src = x + (size_t)(b * NC + c) * IH * IW + t;
    float* colp = s_mem + t * CSTRIDE;
    #pragma unroll
    for (int k = 0; k < 6; ++k) {
      float4 v;
      v.x = src[(size_t)min(base + 4 * k + 0, IH - 1) * IW];
      v.y = src[(size_t)min(base + 4 * k + 1, IH - 1) * IW];
      v.z = src[(size_t)min(base + 4 * k + 2, IH - 1) * IW];
      v.w = src[(size_t)min(base + 4 * k + 3, IH - 1) * IW];
      *(float4*)(colp + 4 * k) = v;
    }
  }
  __syncthreads();

  // x-pass into registers: FIXED 6 taps (zero-padded weights are exact)
  float xr[LROWS];
  #pragma unroll
  for (int r = 0; r < LROWS; ++r) xr[r] = 0.0f;
  if (t < OS) {
    const float4* W4 = (const float4*)(wtab + ((size_t)(b * 2 + 1) * 224 + t) * 8);
    float4 wA = W4[0], wB = W4[1];
    int ix0 = (int)wB.z;
    #pragma unroll
    for (int j = 0; j < 6; ++j) {
      float wj = (j == 0) ? wA.x : (j == 1) ? wA.y : (j == 2) ? wA.z
               : (j == 3) ? wA.w : (j == 4) ? wB.x : wB.y;
      const float* colp = s_mem + (ix0 + j) * CSTRIDE;
      #pragma unroll
      for (int k = 0; k < 6; ++k) {
        float4 f = *(const float4*)(colp + 4 * k);
        xr[4 * k + 0] += wj * f.x;
        xr[4 * k + 1] += wj * f.y;
        xr[4 * k + 2] += wj * f.z;
        xr[4 * k + 3] += wj * f.w;
      }
    }
  }
  __syncthreads();

  // writeback col-major stride 25 (conflict-free; merges to ds_write2_b32)
  {
    float* colq = s_mem + t * YSTR;
    #pragma unroll
    for (int r = 0; r < LROWS; ++r) colq[r] = xr[r];
  }
  __syncthreads();

  // y-pass: LDS-broadcast weights, contiguous column reads, bf16 stores
  float bfac = P[6];
  float psum = 0.0f;
  bool act = (t < OS);
  unsigned short* dst = xcj + ((size_t)(b * NC + c) * OS + oyb) * OS + t;
  const float* colq = s_mem + t * YSTR;
  #pragma unroll 2
  for (int i = 0; i < TROWS; ++i) {
    float4 a = *(const float4*)&s_wyl[i * 8];       // w0..w3 (broadcast)
    float4 h = *(const float4*)&s_wyl[i * 8 + 4];   // w4,w5,iy0,n
    int ry0 = (int)h.z - base;
    const float* p = colq + ry0;
    float acc = a.x * p[0] + a.y * p[1] + a.z * p[2]
              + a.w * p[3] + h.x * p[4] + h.y * p[5];
    if (act) {
      dst[(size_t)i * OS] = f2bf(acc);
      psum += fminf(fmaxf(acc * bfac, 0.0f), 1.0f);
    }
  }
  for (int off = 32; off > 0; off >>= 1) psum += __shfl_down(psum, off, 64);
  int wid = t >> 6, lane = t & 63;
  if (lane == 0) wsum[wid] = psum;
  __syncthreads();
  if (t == 0) rowsum[blk] = wsum[0] + wsum[1] + wsum[2] + wsum[3];
}

__global__ __launch_bounds__(64) void k_means(const float* __restrict__ rowsum,
                                              float* __restrict__ means) {
  int b = blockIdx.x, t = threadIdx.x;
  float acc = 0.0f;
  if (t < NC * NTILE) {
    int c = t / NTILE;
    float w = (c == 0) ? 0.2989f : ((c == 1) ? 0.587f : 0.114f);
    acc = w * rowsum[b * NC * NTILE + t];
  }
  for (int off = 32; off > 0; off >>= 1) acc += __shfl_down(acc, off, 64);
  if (t == 0) means[b] = acc / (float)PIX;
}

// ---------------- color jitter ----------------
__device__ __forceinline__ float clip01(float x) { return fminf(fmaxf(x, 0.0f), 1.0f); }
__device__ __forceinline__ float fmod1(float x)  { return x - floorf(x); }

__device__ __forceinline__ void jitter_px(float& r, float& g, float& bb,
                                          float mg, float bfac, float cfac,
                                          float sfac, float hfac) {
  r = clip01(r * bfac); g = clip01(g * bfac); bb = clip01(bb * bfac);
  r  = clip01(cfac * r  + (1.0f - cfac) * mg);
  g  = clip01(cfac * g  + (1.0f - cfac) * mg);
  bb = clip01(cfac * bb + (1.0f - cfac) * mg);
  float gray = 0.2989f * r + 0.587f * g + 0.114f * bb;
  r  = clip01(sfac * r  + (1.0f - sfac) * gray);
  g  = clip01(sfac * g  + (1.0f - sfac) * gray);
  bb = clip01(sfac * bb + (1.0f - sfac) * gray);
  float maxc = fmaxf(r, fmaxf(g, bb));
  float minc = fminf(r, fminf(g, bb));
  float v = maxc, d = maxc - minc;
  float s = (maxc > 0.0f) ? (d / maxc) : 0.0f;
  float dn = (d > 0.0f) ? d : 1.0f;
  float rc = (maxc - r) / dn, gc = (maxc - g) / dn, bc2 = (maxc - bb) / dn;
  float h = (maxc == r) ? (bc2 - gc)
          : ((maxc == g) ? (2.0f + rc - bc2) : (4.0f + gc - rc));
  h = (d > 0.0f) ? fmod1(h / 6.0f) : 0.0f;
  h = fmod1(h + hfac);
  float fi = floorf(h * 6.0f);
  float f = h * 6.0f - fi;
  int i = ((int)fi) % 6;
  float pp = v * (1.0f - s);
  float q  = v * (1.0f - s * f);
  float tt = v * (1.0f - s * (1.0f - f));
  switch (i) {
    case 0: r = v;  g = tt; bb = pp; break;
    case 1: r = q;  g = v;  bb = pp; break;
    case 2: r = pp; g = v;  bb = tt; break;
    case 3: r = pp; g = q;  bb = v;  break;
    case 4: r = tt; g = pp; bb = v;  break;
    default: r = v; g = pp; bb = q;  break;
  }
}

// 4 px/thread from bf16 xcj. Blur batches: jitter in place (bf16); skip write
// if cj==false (bits already correct). Non-blur: write f32 out.
__global__ __launch_bounds__(256) void k_jitter(unsigned short* __restrict__ xcj,
                                                const float* __restrict__ means,
                                                const float* __restrict__ prm,
                                                float* __restrict__ out) {
  int idx = blockIdx.x * 256 + threadIdx.x;
  const int QPB = PIX / 4;
  if (idx >= NB * QPB) return;
  int b = idx / QPB, p4 = idx - b * QPB;
  const float* P = prm + b * PSTRIDE;
  float bfac = P[6], cfac = P[7], sfac = P[8], hfac = P[9];
  bool cj = P[10] != 0.0f;
  bool bl = P[11] != 0.0f;
  if (bl && !cj) return;                     // xj == xc, bits already in place
  size_t base4 = ((size_t)b * NC * PIX) / 4 + p4;
  ushort4* in4 = (ushort4*)xcj;
  ushort4 ru = in4[base4];
  ushort4 gu = in4[base4 + PIX / 4];
  ushort4 bu = in4[base4 + 2 * (PIX / 4)];
  float4 r4 = make_float4(bf2f(ru.x), bf2f(ru.y), bf2f(ru.z), bf2f(ru.w));
  float4 g4 = make_float4(bf2f(gu.x), bf2f(gu.y), bf2f(gu.z), bf2f(gu.w));
  float4 b4 = make_float4(bf2f(bu.x), bf2f(bu.y), bf2f(bu.z), bf2f(bu.w));
  if (cj) {
    float mg = means[b];
    float* rp = (float*)&r4; float* gp = (float*)&g4; float* bp = (float*)&b4;
    #pragma unroll
    for (int k = 0; k < 4; ++k) jitter_px(rp[k], gp[k], bp[k], mg, bfac, cfac, sfac, hfac);
  }
  if (bl) {
    ushort4 s;
    s.x = f2bf(r4.x); s.y = f2bf(r4.y); s.z = f2bf(r4.z); s.w = f2bf(r4.w);
    in4[base4] = s;
    s.x = f2bf(g4.x); s.y = f2bf(g4.y); s.z = f2bf(g4.z); s.w = f2bf(g4.w);
    in4[base4 + PIX / 4] = s;
    s.x = f2bf(b4.x); s.y = f2bf(b4.y); s.z = f2bf(b4.z); s.w = f2bf(b4.w);
    in4[base4 + 2 * (PIX / 4)] = s;
  } else {
    float4* dst4 = (float4*)out;
    dst4[base4] = r4;
    dst4[base4 + PIX / 4] = g4;
    dst4[base4 + 2 * (PIX / 4)] = b4;
  }
}

// ---------------- separable gaussian blur (reflect), gated per b ----------
// y-pass: contribution trick (bit-identical). mid stored with 8-float
// reflected aprons at stride 240 -> x-pass = 5 aligned ds_read_b128 per
// 4 outputs (contiguous across lanes, conflict-free), k-ascending sums.
__global__ __launch_bounds__(256) void k_blur(const unsigned short* __restrict__ xcj,
                                              float* __restrict__ out,
                                              const float* __restrict__ prm) {
  int blk = blockIdx.x;
  int tile = blk % NTILE;
  int c = (blk / NTILE) % NC;
  int b = blk / (NTILE * NC);
  const float* P = prm + b * PSTRIDE;
  if (P[11] == 0.0f) return;
  int t = threadIdx.x;
  int oyb = tile * TROWS;

  __shared__ unsigned short s_in[TROWS + 14][228];        // 13,680 B (bf16 halo)
  __shared__ __align__(16) float s_mid[TROWS][BSTR];      // 15,360 B (aproned)
  __shared__ float s_k[15];
  if (t < 15) s_k[t] = P[12 + t];

  const unsigned short* plane = xcj + (size_t)(b * NC + c) * PIX;
  float* oplane = out + (size_t)(b * NC + c) * PIX;

  // stage 30 reflected rows as raw bf16 (ushort4 copies)
  {
    const int RQ = OS / 4;                                // 56 quads per row
    for (int f = t; f < (TROWS + 14) * RQ; f += 256) {
      int r = f / RQ, q = f - r * RQ;
      int yy = oyb - 7 + r;
      yy = (yy < 0) ? -yy : ((yy > OS - 1) ? (2 * (OS - 1) - yy) : yy);
      *(ushort4*)&s_in[r][4 * q] = *(const ushort4*)(plane + (size_t)yy * OS + 4 * q);
    }
  }
  __syncthreads();

  // weights to registers via LDS broadcast (proven cheap)
  float w[15];
  #pragma unroll
  for (int k = 0; k < 15; ++k) w[k] = s_k[k];

  // y-pass: contribution trick — 30 reads, 240 static fmacs, exact FP order.
  if (t < OS) {
    float acc[TROWS];
    #pragma unroll
    for (int i = 0; i < TROWS; ++i) acc[i] = 0.0f;
    #pragma unroll
    for (int r = 0; r < TROWS + 14; ++r) {
      float val = bf2f(s_in[r][t]);
      #pragma unroll
      for (int i = 0; i < TROWS; ++i) {
        if (i <= r && r - i <= 14) acc[i] += w[r - i] * val;
      }
    }
    #pragma unroll
    for (int i = 0; i < TROWS; ++i) {
      s_mid[i][8 + t] = acc[i];
      if (t >= 1 && t <= 7)     s_mid[i][8 - t] = acc[i];      // left apron
      if (t >= 216 && t <= 222) s_mid[i][454 - t] = acc[i];    // right apron
    }
  }
  __syncthreads();

  // x-pass: 4 consecutive outputs per work item, 5 aligned b128 window reads.
  #pragma unroll 1
  for (int it = 0; it < 4; ++it) {
    int f = it * 256 + t;
    if (f < TROWS * 56) {
      int r = f / 56, q = f - r * 56;
      const float* row = &s_mid[r][0];
      float v[20];
      *(float4*)&v[0]  = *(const float4*)(row + 4 * q);
      *(float4*)&v[4]  = *(const float4*)(row + 4 * q + 4);
      *(float4*)&v[8]  = *(const float4*)(row + 4 * q + 8);
      *(float4*)&v[12] = *(const float4*)(row + 4 * q + 12);
      *(float4*)&v[16] = *(const float4*)(row + 4 * q + 16);
      float4 o;
      float* op = (float*)&o;
      #pragma unroll
      for (int m = 0; m < 4; ++m) {
        float acc = 0.0f;
        #pragma unroll
        for (int k = 0; k < 15; ++k) acc += w[k] * v[m + k + 1];
        op[m] = acc;
      }
      *(float4*)(oplane + (size_t)(oyb + r) * OS + 4 * q) = o;
    }
  }
}

// ---------------- launch ----------------
extern "C" void kernel_launch(void* const* d_in, const int* in_sizes, int n_in,
                              void* d_out, int out_size, void* d_ws, size_t ws_size,
                              hipStream_t stream) {
  const float* x = (const float*)d_in[0];
  float* out = (float*)d_out;
  char* ws = (char*)d_ws;

  float* prm    = (float*)ws;                            // 32768 B
  float* rowsum = (float*)(ws + 32768);                  // 43008 B
  float* means  = (float*)(ws + 75776);                  // 1024 B
  float* wtab   = (float*)(ws + 76800);                  // 3670016 B
  unsigned short* xcj = (unsigned short*)(ws + 3746816); // 77070336 B (bf16 xc/xj)

  k_params<<<1, 256, 0, stream>>>(prm);
  k_weights<<<NB * 2, 224, 0, stream>>>(prm, wtab);

  int nblk = NB * NC * NTILE;                            // 10752
  k_resize<<<nblk, 256, 0, stream>>>(x, xcj, rowsum, prm, wtab);  // xc -> xcj
  k_means<<<NB, 64, 0, stream>>>(rowsum, means);

  int nquad = NB * (PIX / 4);                            // 3211264
  k_jitter<<<(nquad + 255) / 256, 256, 0, stream>>>(xcj, means, prm, out);

  k_blur<<<nblk, 256, 0, stream>>>(xcj, out, prm);       // blurred b: xcj -> out
}

// Round 12
// 171.352 us; speedup vs baseline: 1.0748x; 1.0356x over previous
//
#include <hip/hip_runtime.h>
#include <cstdint>
#include <cstddef>

// ============================================================================
// MildAugmentStage: random-resized-crop (cubic, antialias) + color jitter +
// separable gaussian blur, reproducing jax.random (threefry2x32) exactly.
// Round 11: EXACT round-8 configuration (best measured: 170.3 us).
// - resize: col-major b128 staging, fixed trip counts, stride-25 y-buffer,
//   s_wyl LDS-broadcast y-weights (uniform-global variant regressed, r9).
// - blur: contiguous-lane b32 x-pass (sliding-window variant regressed, r10).
// - bf16 xc/xj single in-place buffer; jitter skips write when bl&&!cj.
// ============================================================================

#define JAX_PARTITIONABLE 1

#define NB 256
#define NC 3
#define IH 256
#define IW 256
#define OS 224
#define PIX (OS * OS)         // 50176
#define PSTRIDE 32
#define TROWS 16              // output rows per resize/blur tile
#define LROWS 24              // max staged input rows
#define NTILE 14              // 224/16
#define CSTRIDE 28            // dwords per staged column (112 B)
#define YSTR 25               // y-buffer column stride (gcd(25,32)=1)

// ---------------- bf16 helpers ----------------
__device__ __forceinline__ float bf2f(unsigned short u) {
  return __uint_as_float(((unsigned)u) << 16);
}
__device__ __forceinline__ unsigned short f2bf(float f) {
  unsigned u = __float_as_uint(f);
  return (unsigned short)((u + 0x7FFFu + ((u >> 16) & 1u)) >> 16);
}

// ---------------- threefry-2x32 ----------------
__device__ __forceinline__ void tf2x32(uint32_t k0, uint32_t k1,
                                       uint32_t x0, uint32_t x1,
                                       uint32_t& o0, uint32_t& o1) {
  uint32_t ks[3] = {k0, k1, k0 ^ k1 ^ 0x1BD11BDAu};
  uint32_t a = x0 + ks[0], b = x1 + ks[1];
  const int R[2][4] = {{13, 15, 26, 6}, {17, 29, 16, 24}};
  #pragma unroll
  for (int i = 0; i < 5; ++i) {
    #pragma unroll
    for (int j = 0; j < 4; ++j) {
      int r = R[i & 1][j];
      a += b;
      b = (b << r) | (b >> (32 - r));
      b ^= a;
    }
    a += ks[(i + 1) % 3];
    b += ks[(i + 2) % 3] + (uint32_t)(i + 1);
  }
  o0 = a; o1 = b;
}

__device__ __forceinline__ float bits_to_u01(uint32_t bits) {
  uint32_t fb = (bits >> 9) | 0x3f800000u;
  return __uint_as_float(fb) - 1.0f;
}

__device__ __forceinline__ float u01_n(uint32_t k0, uint32_t k1, uint32_t i, uint32_t N) {
#if JAX_PARTITIONABLE
  uint32_t a, b; tf2x32(k0, k1, 0u, i, a, b);
  return bits_to_u01(a ^ b);
#else
  uint32_t half = N >> 1;
  uint32_t a, b;
  if (i < half) { tf2x32(k0, k1, i, half + i, a, b); return bits_to_u01(a); }
  tf2x32(k0, k1, i - half, i, a, b); return bits_to_u01(b);
#endif
}

__device__ __forceinline__ float junif(uint32_t k0, uint32_t k1, uint32_t i, uint32_t N,
                                       float mn, float mx) {
  float u = u01_n(k0, k1, i, N);
  float d = __fsub_rn(mx, mn);
  float r = __fadd_rn(__fmul_rn(u, d), mn);
  return fmaxf(mn, r);
}

// ---------------- per-batch augmentation parameters ----------------
__global__ __launch_bounds__(256) void k_params(float* __restrict__ prm) {
  int b = threadIdx.x;
  if (b >= NB) return;
  uint32_t ks[10][2];
#if JAX_PARTITIONABLE
  for (int j = 0; j < 10; ++j) tf2x32(0u, 42u, 0u, (uint32_t)j, ks[j][0], ks[j][1]);
#else
  {
    uint32_t flat[20];
    for (int j = 0; j < 10; ++j) {
      uint32_t a, bb; tf2x32(0u, 42u, (uint32_t)j, (uint32_t)(10 + j), a, bb);
      flat[j] = a; flat[10 + j] = bb;
    }
    for (int j = 0; j < 10; ++j) { ks[j][0] = flat[2 * j]; ks[j][1] = flat[2 * j + 1]; }
  }
#endif
  float* P = prm + b * PSTRIDE;

  float uarea = junif(ks[0][0], ks[0][1], b, NB, 0.8f, 1.0f);
  float area  = __fmul_rn(65536.0f, uarea);
  float lmn = (float)(-0.28768207245178085);
  float lmx = (float)( 0.28768207245178085);
  float ur  = junif(ks[1][0], ks[1][1], b, NB, lmn, lmx);
  float ratio = (float)exp((double)ur);

  float cw = rintf(__fsqrt_rn(__fmul_rn(area, ratio)));
  cw = fminf(fmaxf(cw, 1.0f), 256.0f);
  float ch = rintf(__fsqrt_rn(__fdiv_rn(area, ratio)));
  ch = fminf(fmaxf(ch, 1.0f), 256.0f);

  float ui = u01_n(ks[2][0], ks[2][1], b, NB);
  float uj = u01_n(ks[3][0], ks[3][1], b, NB);
  float i0 = floorf(__fmul_rn(ui, __fadd_rn(__fsub_rn(256.0f, ch), 1.0f)));
  float j0 = floorf(__fmul_rn(uj, __fadd_rn(__fsub_rn(256.0f, cw), 1.0f)));

  float sy = __fdiv_rn(224.0f, ch), sx = __fdiv_rn(224.0f, cw);
  float ty = -__fmul_rn(i0, sy),   tx = -__fmul_rn(j0, sx);
  float inv_sy = __fdiv_rn(1.0f, sy), inv_sx = __fdiv_rn(1.0f, sx);
  P[0] = inv_sy;
  P[1] = __fmul_rn(ty, inv_sy);
  P[2] = fmaxf(inv_sy, 1.0f);
  P[3] = inv_sx;
  P[4] = __fmul_rn(tx, inv_sx);
  P[5] = fmaxf(inv_sx, 1.0f);

  P[6] = junif(ks[4][0], ks[4][1], b, NB, 0.9f, 1.1f);
  P[7] = junif(ks[5][0], ks[5][1], b, NB, 0.9f, 1.1f);
  P[8] = junif(ks[6][0], ks[6][1], b, NB, 0.9f, 1.1f);
  P[9] = junif(ks[7][0], ks[7][1], b, NB, -0.01f, 0.01f);
  P[10] = (u01_n(ks[8][0], ks[8][1], b, NB) < 0.8f) ? 1.0f : 0.0f;

  uint32_t kb0[2], kb1[2];
#if JAX_PARTITIONABLE
  tf2x32(ks[9][0], ks[9][1], 0u, 0u, kb0[0], kb0[1]);
  tf2x32(ks[9][0], ks[9][1], 0u, 1u, kb1[0], kb1[1]);
#else
  {
    uint32_t f0, s0, f1, s1;
    tf2x32(ks[9][0], ks[9][1], 0u, 2u, f0, s0);
    tf2x32(ks[9][0], ks[9][1], 1u, 3u, f1, s1);
    kb0[0] = f0; kb0[1] = f1; kb1[0] = s0; kb1[1] = s1;
  }
#endif
  float sg = junif(kb0[0], kb0[1], b, NB, 0.1f, 2.0f);
  P[11] = (u01_n(kb1[0], kb1[1], b, NB) < 0.5f) ? 1.0f : 0.0f;

  float e[15]; float ssum = 0.0f;
  for (int k = 0; k < 15; ++k) {
    float t = (float)k - 7.0f;
    float z = t / sg;
    e[k] = expf(-0.5f * (z * z));
    ssum += e[k];
  }
  for (int k = 0; k < 15; ++k) P[12 + k] = e[k] / ssum;
}

// ---------------- cubic (Keys, a=-0.5) ----------------
__device__ __forceinline__ float keys_cubic(float x) {
  float o = ((1.5f * x - 2.5f) * x) * x + 1.0f;
  if (x >= 1.0f) o = ((-0.5f * x + 2.5f) * x - 4.0f) * x + 2.0f;
  if (x >= 2.0f) o = 0.0f;
  return o;
}

// ---------------- per-batch resize weight tables ----------------
// wtab[b][dim(0=y,1=x)][o][8]: w0..w5 (zero-padded), i0, ntaps
__global__ __launch_bounds__(224) void k_weights(const float* __restrict__ prm,
                                                 float* __restrict__ wtab) {
  int o = threadIdx.x;
  int dim = blockIdx.x & 1;
  int b = blockIdx.x >> 1;
  const float* P = prm + b * PSTRIDE;
  float inv = dim ? P[3] : P[0];
  float ti  = dim ? P[4] : P[1];
  float ks  = dim ? P[5] : P[2];
  float sf = ((float)o + 0.5f) * inv - ti - 0.5f;
  float r = 2.0f * ks;
  int i0 = max(0, (int)ceilf(sf - r));
  int i1 = min(255, (int)floorf(sf + r));
  int n = i1 - i0 + 1; if (n > 6) n = 6;
  float w[6]; float tot = 0.0f;
  #pragma unroll
  for (int j = 0; j < 6; ++j) {
    float v = 0.0f;
    if (j < n) { float d = fabsf(sf - (float)(i0 + j)) / ks; v = keys_cubic(d); }
    w[j] = v; tot += v;
  }
  float ri = (fabsf(tot) > 1.1920929e-4f) ? (1.0f / tot) : 0.0f;
  float* W = wtab + ((size_t)(b * 2 + dim) * 224 + o) * 8;
  #pragma unroll
  for (int j = 0; j < 6; ++j) W[j] = w[j] * ri;
  W[6] = (float)i0;
  W[7] = (float)n;
}

// ---------------- tiled separable resize (bf16 out) ----------------
__global__ __launch_bounds__(256) void k_resize(const float* __restrict__ x,
                                                unsigned short* __restrict__ xcj,
                                                float* __restrict__ rowsum,
                                                const float* __restrict__ prm,
                                                const float* __restrict__ wtab) {
  int blk = blockIdx.x;
  int tile = blk % NTILE;
  int c = (blk / NTILE) % NC;
  int b = blk / (NTILE * NC);
  int t = threadIdx.x;
  int oyb = tile * TROWS;
  const float* P = prm + b * PSTRIDE;
  const float* wty = wtab + ((size_t)(b * 2) * 224 + oyb) * 8;

  __shared__ __align__(16) float s_mem[256 * CSTRIDE];   // 28672 B
  __shared__ __align__(16) float s_wyl[TROWS * 8];       // 512 B y-weight block
  __shared__ float wsum[4];

  if (t < TROWS * 8) s_wyl[t] = wty[t];

  int base = (int)wty[6];

  // stage column t: FIXED 6 chunks of 4 rows (row-clamped), b128 writes
  {
    const float* src = x + (size_t)(b * NC + c) * IH * IW + t;
    float* colp = s_mem + t * CSTRIDE;
    #pragma unroll
    for (int k = 0; k < 6; ++k) {
      float4 v;
      v.x = src[(size_t)min(base + 4 * k + 0, IH - 1) * IW];
      v.y = src[(size_t)min(base + 4 * k + 1, IH - 1) * IW];
      v.z = src[(size_t)min(base + 4 * k + 2, IH - 1) * IW];
      v.w = src[(size_t)min(base + 4 * k + 3, IH - 1) * IW];
      *(float4*)(colp + 4 * k) = v;
    }
  }
  __syncthreads();

  // x-pass into registers: FIXED 6 taps (zero-padded weights are exact)
  float xr[LROWS];
  #pragma unroll
  for (int r = 0; r < LROWS; ++r) xr[r] = 0.0f;
  if (t < OS) {
    const float4* W4 = (const float4*)(wtab + ((size_t)(b * 2 + 1) * 224 + t) * 8);
    float4 wA = W4[0], wB = W4[1];
    int ix0 = (int)wB.z;
    #pragma unroll
    for (int j = 0; j < 6; ++j) {
      float wj = (j == 0) ? wA.x : (j == 1) ? wA.y : (j == 2) ? wA.z
               : (j == 3) ? wA.w : (j == 4) ? wB.x : wB.y;
      const float* colp = s_mem + (ix0 + j) * CSTRIDE;
      #pragma unroll
      for (int k = 0; k < 6; ++k) {
        float4 f = *(const float4*)(colp + 4 * k);
        xr[4 * k + 0] += wj * f.x;
        xr[4 * k + 1] += wj * f.y;
        xr[4 * k + 2] += wj * f.z;
        xr[4 * k + 3] += wj * f.w;
      }
    }
  }
  __syncthreads();

  // writeback col-major stride 25 (conflict-free; merges to ds_write2_b32)
  {
    float* colq = s_mem + t * YSTR;
    #pragma unroll
    for (int r = 0; r < LROWS; ++r) colq[r] = xr[r];
  }
  __syncthreads();

  // y-pass: LDS-broadcast weights, contiguous column reads, bf16 stores
  float bfac = P[6];
  float psum = 0.0f;
  bool act = (t < OS);
  unsigned short* dst = xcj + ((size_t)(b * NC + c) * OS + oyb) * OS + t;
  const float* colq = s_mem + t * YSTR;
  #pragma unroll 2
  for (int i = 0; i < TROWS; ++i) {
    float4 a = *(const float4*)&s_wyl[i * 8];       // w0..w3 (broadcast)
    float4 h = *(const float4*)&s_wyl[i * 8 + 4];   // w4,w5,iy0,n
    int ry0 = (int)h.z - base;
    const float* p = colq + ry0;
    float acc = a.x * p[0] + a.y * p[1] + a.z * p[2]
              + a.w * p[3] + h.x * p[4] + h.y * p[5];
    if (act) {
      dst[(size_t)i * OS] = f2bf(acc);
      psum += fminf(fmaxf(acc * bfac, 0.0f), 1.0f);
    }
  }
  for (int off = 32; off > 0; off >>= 1) psum += __shfl_down(psum, off, 64);
  int wid = t >> 6, lane = t & 63;
  if (lane == 0) wsum[wid] = psum;
  __syncthreads();
  if (t == 0) rowsum[blk] = wsum[0] + wsum[1] + wsum[2] + wsum[3];
}

__global__ __launch_bounds__(64) void k_means(const float* __restrict__ rowsum,
                                              float* __restrict__ means) {
  int b = blockIdx.x, t = threadIdx.x;
  float acc = 0.0f;
  if (t < NC * NTILE) {
    int c = t / NTILE;
    float w = (c == 0) ? 0.2989f : ((c == 1) ? 0.587f : 0.114f);
    acc = w * rowsum[b * NC * NTILE + t];
  }
  for (int off = 32; off > 0; off >>= 1) acc += __shfl_down(acc, off, 64);
  if (t == 0) means[b] = acc / (float)PIX;
}

// ---------------- color jitter ----------------
__device__ __forceinline__ float clip01(float x) { return fminf(fmaxf(x, 0.0f), 1.0f); }
__device__ __forceinline__ float fmod1(float x)  { return x - floorf(x); }

__device__ __forceinline__ void jitter_px(float& r, float& g, float& bb,
                                          float mg, float bfac, float cfac,
                                          float sfac, float hfac) {
  r = clip01(r * bfac); g = clip01(g * bfac); bb = clip01(bb * bfac);
  r  = clip01(cfac * r  + (1.0f - cfac) * mg);
  g  = clip01(cfac * g  + (1.0f - cfac) * mg);
  bb = clip01(cfac * bb + (1.0f - cfac) * mg);
  float gray = 0.2989f * r + 0.587f * g + 0.114f * bb;
  r  = clip01(sfac * r  + (1.0f - sfac) * gray);
  g  = clip01(sfac * g  + (1.0f - sfac) * gray);
  bb = clip01(sfac * bb + (1.0f - sfac) * gray);
  float maxc = fmaxf(r, fmaxf(g, bb));
  float minc = fminf(r, fminf(g, bb));
  float v = maxc, d = maxc - minc;
  float s = (maxc > 0.0f) ? (d / maxc) : 0.0f;
  float dn = (d > 0.0f) ? d : 1.0f;
  float rc = (maxc - r) / dn, gc = (maxc - g) / dn, bc2 = (maxc - bb) / dn;
  float h = (maxc == r) ? (bc2 - gc)
          : ((maxc == g) ? (2.0f + rc - bc2) : (4.0f + gc - rc));
  h = (d > 0.0f) ? fmod1(h / 6.0f) : 0.0f;
  h = fmod1(h + hfac);
  float fi = floorf(h * 6.0f);
  float f = h * 6.0f - fi;
  int i = ((int)fi) % 6;
  float pp = v * (1.0f - s);
  float q  = v * (1.0f - s * f);
  float tt = v * (1.0f - s * (1.0f - f));
  switch (i) {
    case 0: r = v;  g = tt; bb = pp; break;
    case 1: r = q;  g = v;  bb = pp; break;
    case 2: r = pp; g = v;  bb = tt; break;
    case 3: r = pp; g = q;  bb = v;  break;
    case 4: r = tt; g = pp; bb = v;  break;
    default: r = v; g = pp; bb = q;  break;
  }
}

// 4 px/thread from bf16 xcj. Blur batches: jitter in place (bf16); skip write
// if cj==false (bits already correct). Non-blur: write f32 out.
__global__ __launch_bounds__(256) void k_jitter(unsigned short* __restrict__ xcj,
                                                const float* __restrict__ means,
                                                const float* __restrict__ prm,
                                                float* __restrict__ out) {
  int idx = blockIdx.x * 256 + threadIdx.x;
  const int QPB = PIX / 4;
  if (idx >= NB * QPB) return;
  int b = idx / QPB, p4 = idx - b * QPB;
  const float* P = prm + b * PSTRIDE;
  float bfac = P[6], cfac = P[7], sfac = P[8], hfac = P[9];
  bool cj = P[10] != 0.0f;
  bool bl = P[11] != 0.0f;
  if (bl && !cj) return;                     // xj == xc, bits already in place
  size_t base4 = ((size_t)b * NC * PIX) / 4 + p4;
  ushort4* in4 = (ushort4*)xcj;
  ushort4 ru = in4[base4];
  ushort4 gu = in4[base4 + PIX / 4];
  ushort4 bu = in4[base4 + 2 * (PIX / 4)];
  float4 r4 = make_float4(bf2f(ru.x), bf2f(ru.y), bf2f(ru.z), bf2f(ru.w));
  float4 g4 = make_float4(bf2f(gu.x), bf2f(gu.y), bf2f(gu.z), bf2f(gu.w));
  float4 b4 = make_float4(bf2f(bu.x), bf2f(bu.y), bf2f(bu.z), bf2f(bu.w));
  if (cj) {
    float mg = means[b];
    float* rp = (float*)&r4; float* gp = (float*)&g4; float* bp = (float*)&b4;
    #pragma unroll
    for (int k = 0; k < 4; ++k) jitter_px(rp[k], gp[k], bp[k], mg, bfac, cfac, sfac, hfac);
  }
  if (bl) {
    ushort4 s;
    s.x = f2bf(r4.x); s.y = f2bf(r4.y); s.z = f2bf(r4.z); s.w = f2bf(r4.w);
    in4[base4] = s;
    s.x = f2bf(g4.x); s.y = f2bf(g4.y); s.z = f2bf(g4.z); s.w = f2bf(g4.w);
    in4[base4 + PIX / 4] = s;
    s.x = f2bf(b4.x); s.y = f2bf(b4.y); s.z = f2bf(b4.z); s.w = f2bf(b4.w);
    in4[base4 + 2 * (PIX / 4)] = s;
  } else {
    float4* dst4 = (float4*)out;
    dst4[base4] = r4;
    dst4[base4 + PIX / 4] = g4;
    dst4[base4 + 2 * (PIX / 4)] = b4;
  }
}

// ---------------- separable gaussian blur (reflect), gated per b ----------
// staging: raw bf16 halo copy; y-pass: contribution trick into acc[16]
// (bit-identical k-ascending order); x-pass: contiguous-lane b32 reads
// (conflict-free), weights in registers.
__global__ __launch_bounds__(256) void k_blur(const unsigned short* __restrict__ xcj,
                                              float* __restrict__ out,
                                              const float* __restrict__ prm) {
  int blk = blockIdx.x;
  int tile = blk % NTILE;
  int c = (blk / NTILE) % NC;
  int b = blk / (NTILE * NC);
  const float* P = prm + b * PSTRIDE;
  if (P[11] == 0.0f) return;
  int t = threadIdx.x;
  int oyb = tile * TROWS;

  __shared__ unsigned short s_in[TROWS + 14][228];   // 13,680 B (bf16 halo)
  __shared__ float s_mid[TROWS][226];                // 14,464 B
  __shared__ float s_k[15];
  if (t < 15) s_k[t] = P[12 + t];

  const unsigned short* plane = xcj + (size_t)(b * NC + c) * PIX;
  float* oplane = out + (size_t)(b * NC + c) * PIX;

  // stage 30 reflected rows as raw bf16 (ushort4 copies)
  {
    const int RQ = OS / 4;                           // 56 quads per row
    for (int f = t; f < (TROWS + 14) * RQ; f += 256) {
      int r = f / RQ, q = f - r * RQ;
      int yy = oyb - 7 + r;
      yy = (yy < 0) ? -yy : ((yy > OS - 1) ? (2 * (OS - 1) - yy) : yy);
      *(ushort4*)&s_in[r][4 * q] = *(const ushort4*)(plane + (size_t)yy * OS + 4 * q);
    }
  }
  __syncthreads();

  // weights to registers (broadcast reads, once)
  float w[15];
  #pragma unroll
  for (int k = 0; k < 15; ++k) w[k] = s_k[k];

  // y-pass: contribution trick — 30 reads, 240 static fmacs, exact FP order
  float acc[TROWS];
  #pragma unroll
  for (int i = 0; i < TROWS; ++i) acc[i] = 0.0f;
  if (t < OS) {
    #pragma unroll
    for (int r = 0; r < TROWS + 14; ++r) {
      float val = bf2f(s_in[r][t]);
      #pragma unroll
      for (int i = 0; i < TROWS; ++i) {
        if (i <= r && r - i <= 14) acc[i] += w[r - i] * val;
      }
    }
    #pragma unroll
    for (int i = 0; i < TROWS; ++i) s_mid[i][t] = acc[i];
  }
  __syncthreads();

  // x-pass with reflect, weights from registers (lanes contiguous per k:
  // conflict-free b32 pattern — faster than the r9/r10 sliding-window variant)
  if (t < OS) {
    for (int i = 0; i < TROWS; ++i) {
      float a2 = 0.0f;
      #pragma unroll
      for (int k = 0; k < 15; ++k) {
        int xx = t - 7 + k;
        xx = (xx < 0) ? -xx : ((xx > OS - 1) ? (2 * (OS - 1) - xx) : xx);
        a2 += w[k] * s_mid[i][xx];
      }
      oplane[(size_t)(oyb + i) * OS + t] = a2;
    }
  }
}

// ---------------- launch ----------------
extern "C" void kernel_launch(void* const* d_in, const int* in_sizes, int n_in,
                              void* d_out, int out_size, void* d_ws, size_t ws_size,
                              hipStream_t stream) {
  const float* x = (const float*)d_in[0];
  float* out = (float*)d_out;
  char* ws = (char*)d_ws;

  float* prm    = (float*)ws;                            // 32768 B
  float* rowsum = (float*)(ws + 32768);                  // 43008 B
  float* means  = (float*)(ws + 75776);                  // 1024 B
  float* wtab   = (float*)(ws + 76800);                  // 3670016 B
  unsigned short* xcj = (unsigned short*)(ws + 3746816); // 77070336 B (bf16 xc/xj)

  k_params<<<1, 256, 0, stream>>>(prm);
  k_weights<<<NB * 2, 224, 0, stream>>>(prm, wtab);

  int nblk = NB * NC * NTILE;                            // 10752
  k_resize<<<nblk, 256, 0, stream>>>(x, xcj, rowsum, prm, wtab);  // xc -> xcj
  k_means<<<NB, 64, 0, stream>>>(rowsum, means);

  int nquad = NB * (PIX / 4);                            // 3211264
  k_jitter<<<(nquad + 255) / 256, 256, 0, stream>>>(xcj, means, prm, out);

  k_blur<<<nblk, 256, 0, stream>>>(xcj, out, prm);       // blurred b: xcj -> out
}